// Round 1
// baseline (440.952 us; speedup 1.0000x reference)
//
#include <hip/hip_runtime.h>
#include <hip/hip_bf16.h>

// Connected filter:
//   vals[i] = sigmoid(clamp(100*(attrs[i]·w + b), ±12)) * residue[i]
//   cum[i]  = sum of vals along parent chain from i up to root (dummy N terminates)
//   out[p]  = cum[pixel_to_node[p]]
// parent[i] < i (topological), parent[N] = N (dummy, val 0).

// ---------------- Kernel 1: gate + pack (par, val) into 8B records ------------
__global__ void k_gate_pack(const float* __restrict__ attrs,
                            const float* __restrict__ w,
                            const float* __restrict__ bias,
                            const float* __restrict__ residue,
                            const int*   __restrict__ parent,
                            int2* __restrict__ packed,   // .x = par, .y = val bits
                            int N) {
    int i = blockIdx.x * blockDim.x + threadIdx.x;
    if (i > N) return;
    if (i == N) {
        int2 p; p.x = N; p.y = __float_as_int(0.0f);
        packed[N] = p;
        return;
    }
    // row i: 6 floats, 24B stride -> three aligned float2 loads (24*i % 8 == 0)
    const float2* a2 = reinterpret_cast<const float2*>(attrs + (size_t)i * 6);
    float2 a0 = a2[0], a1 = a2[1], a2v = a2[2];
    float logit = bias[0]
                + a0.x  * w[0] + a0.y  * w[1]
                + a1.x  * w[2] + a1.y  * w[3]
                + a2v.x * w[4] + a2v.y * w[5];
    float s = fminf(fmaxf(100.0f * logit, -12.0f), 12.0f);
    float gate = 1.0f / (1.0f + __expf(-s));
    float v = gate * residue[i];
    int2 p; p.x = parent[i]; p.y = __float_as_int(v);
    packed[i] = p;
}

// Split variant (small ws): write vals only, parent read separately later.
__global__ void k_gate_vals(const float* __restrict__ attrs,
                            const float* __restrict__ w,
                            const float* __restrict__ bias,
                            const float* __restrict__ residue,
                            float* __restrict__ vals,
                            int N) {
    int i = blockIdx.x * blockDim.x + threadIdx.x;
    if (i > N) return;
    if (i == N) { vals[N] = 0.0f; return; }
    const float2* a2 = reinterpret_cast<const float2*>(attrs + (size_t)i * 6);
    float2 a0 = a2[0], a1 = a2[1], a2v = a2[2];
    float logit = bias[0]
                + a0.x  * w[0] + a0.y  * w[1]
                + a1.x  * w[2] + a1.y  * w[3]
                + a2v.x * w[4] + a2v.y * w[5];
    float s = fminf(fmaxf(100.0f * logit, -12.0f), 12.0f);
    float gate = 1.0f / (1.0f + __expf(-s));
    vals[i] = gate * residue[i];
}

// ---------------- Kernel 2: per-node chain walk ------------------------------
__global__ void k_walk_packed(const int2* __restrict__ packed,
                              float* __restrict__ cum, int N) {
    int i = blockIdx.x * blockDim.x + threadIdx.x;
    if (i >= N) return;
    float s = 0.0f;
    int j = i;
    while (j != N) {
        int2 pv = packed[j];          // single 8B gather: (par, val)
        s += __int_as_float(pv.y);
        j = pv.x;
    }
    cum[i] = s;
}

__global__ void k_walk_split(const float* __restrict__ vals,
                             const int* __restrict__ parent,
                             float* __restrict__ cum, int N) {
    int i = blockIdx.x * blockDim.x + threadIdx.x;
    if (i >= N) return;
    float s = 0.0f;
    int j = i;
    while (j != N) {
        float v = vals[j];
        int p = parent[j];
        s += v;
        j = p;
    }
    cum[i] = s;
}

// ---------------- Kernel 3: pixel gather, x4 vectorized ----------------------
__global__ void k_pixel_gather(const float* __restrict__ cum,
                               const int* __restrict__ ptn,
                               float* __restrict__ out, int M) {
    int t = blockIdx.x * blockDim.x + threadIdx.x;
    int base = t * 4;
    if (base + 3 < M) {
        int4 idx = reinterpret_cast<const int4*>(ptn)[t];
        float4 o;
        o.x = cum[idx.x];
        o.y = cum[idx.y];
        o.z = cum[idx.z];
        o.w = cum[idx.w];
        reinterpret_cast<float4*>(out)[t] = o;
    } else {
        for (int p = base; p < M; ++p) out[p] = cum[ptn[p]];
    }
}

extern "C" void kernel_launch(void* const* d_in, const int* in_sizes, int n_in,
                              void* d_out, int out_size, void* d_ws, size_t ws_size,
                              hipStream_t stream) {
    const float* attrs   = (const float*)d_in[0];   // (N,6)
    const float* weight  = (const float*)d_in[1];   // (6,)
    const float* bias    = (const float*)d_in[2];   // (1,)
    const float* residue = (const float*)d_in[3];   // (N,)
    const int*   parent  = (const int*)d_in[4];     // (N+1,)
    const int*   ptn     = (const int*)d_in[5];     // (H*W,)
    float* out = (float*)d_out;

    const int N  = in_sizes[3];
    const int HW = in_sizes[5];

    const int BLK = 256;
    const size_t packedBytes = (size_t)(N + 1) * 8;
    const size_t cumBytes    = (size_t)(N + 1) * 4;

    if (ws_size >= packedBytes + cumBytes) {
        int2*  packed = (int2*)d_ws;
        float* cum    = (float*)((char*)d_ws + packedBytes);

        int g1 = (N + 1 + BLK - 1) / BLK;
        k_gate_pack<<<g1, BLK, 0, stream>>>(attrs, weight, bias, residue, parent,
                                            packed, N);
        int g2 = (N + BLK - 1) / BLK;
        k_walk_packed<<<g2, BLK, 0, stream>>>(packed, cum, N);

        int nQuads = (HW + 3) / 4;
        int g3 = (nQuads + BLK - 1) / BLK;
        k_pixel_gather<<<g3, BLK, 0, stream>>>(cum, ptn, out, HW);
    } else {
        // split layout: vals (N+1 floats) + cum (N floats)
        float* vals = (float*)d_ws;
        float* cum  = (float*)((char*)d_ws + cumBytes);

        int g1 = (N + 1 + BLK - 1) / BLK;
        k_gate_vals<<<g1, BLK, 0, stream>>>(attrs, weight, bias, residue, vals, N);
        int g2 = (N + BLK - 1) / BLK;
        k_walk_split<<<g2, BLK, 0, stream>>>(vals, parent, cum, N);

        int nQuads = (HW + 3) / 4;
        int g3 = (nQuads + BLK - 1) / BLK;
        k_pixel_gather<<<g3, BLK, 0, stream>>>(cum, ptn, out, HW);
    }
}

// Round 2
// 377.464 us; speedup vs baseline: 1.1682x; 1.1682x over previous
//
#include <hip/hip_runtime.h>
#include <hip/hip_bf16.h>

// Connected filter:
//   vals[i] = sigmoid(clamp(100*(attrs[i]·w + b), ±12)) * residue[i]
//   cum[i]  = sum of vals along parent chain from i up to root (dummy N terminates)
//   out[p]  = cum[pixel_to_node[p]]
// parent[i] < i (topological), parent[N] = N (dummy, val 0).
//
// Walk is computed in LEVELS: nodes in [cutoff_{k-1}, cutoff_k) walk only until
// their chain drops below cutoff_{k-1} (expected ~ln(16)=1.8 random hops, since
// parent[i] ~ uniform[0,i)), then add the already-computed cum of that ancestor.
// This cuts cold random gathers ~3x vs the full walk (node j is visited ~N/j
// times; full walks burn ~19M visits in the cold >64K region).

// ---------------- Kernel 1: gate + pack (par, val) into 8B records ------------
__global__ void k_gate_pack(const float* __restrict__ attrs,
                            const float* __restrict__ w,
                            const float* __restrict__ bias,
                            const float* __restrict__ residue,
                            const int*   __restrict__ parent,
                            int2* __restrict__ packed,   // .x = par, .y = val bits
                            int N) {
    int i = blockIdx.x * blockDim.x + threadIdx.x;
    if (i > N) return;
    if (i == N) {
        int2 p; p.x = N; p.y = __float_as_int(0.0f);
        packed[N] = p;
        return;
    }
    // row i: 6 floats, 24B stride -> three aligned float2 loads (24*i % 8 == 0)
    const float2* a2 = reinterpret_cast<const float2*>(attrs + (size_t)i * 6);
    float2 a0 = a2[0], a1 = a2[1], a2v = a2[2];
    float logit = bias[0]
                + a0.x  * w[0] + a0.y  * w[1]
                + a1.x  * w[2] + a1.y  * w[3]
                + a2v.x * w[4] + a2v.y * w[5];
    float s = fminf(fmaxf(100.0f * logit, -12.0f), 12.0f);
    float gate = 1.0f / (1.0f + __expf(-s));
    float v = gate * residue[i];
    int2 p; p.x = parent[i]; p.y = __float_as_int(v);
    packed[i] = p;
}

// ---------------- Kernel 2a: full walk for the base prefix [0, hi) -----------
__global__ void k_walk_lvl0(const int2* __restrict__ packed,
                            float* __restrict__ cum, int hi, int N) {
    int i = blockIdx.x * blockDim.x + threadIdx.x;
    if (i >= hi) return;
    float s = 0.0f;
    int j = i;
    while (j != N) {               // chain stays < hi (parent[i] < i); hot data
        int2 pv = packed[j];
        s += __int_as_float(pv.y);
        j = pv.x;
    }
    cum[i] = s;
}

// ---------------- Kernel 2b: leveled walk for [lo, hi), stop below cutoff ----
__global__ void k_walk_lvl(const int2* __restrict__ packed,
                           float* __restrict__ cum, int lo, int hi, int cutoff) {
    int i = lo + blockIdx.x * blockDim.x + threadIdx.x;
    if (i >= hi) return;
    float s = 0.0f;
    int j = i;
    do {                            // first load is coalesced (j == i == lane-seq)
        int2 pv = packed[j];
        s += __int_as_float(pv.y);
        j = pv.x;
    } while (j >= cutoff);          // parent[j] < j, so this terminates
    cum[i] = s + cum[j];            // ancestor cum from hot prefix (< cutoff)
}

// ---------------- Kernel 3: pixel gather, x4 vectorized ----------------------
__global__ void k_pixel_gather(const float* __restrict__ cum,
                               const int* __restrict__ ptn,
                               float* __restrict__ out, int M) {
    int t = blockIdx.x * blockDim.x + threadIdx.x;
    int base = t * 4;
    if (base + 3 < M) {
        int4 idx = reinterpret_cast<const int4*>(ptn)[t];
        float4 o;
        o.x = cum[idx.x];
        o.y = cum[idx.y];
        o.z = cum[idx.z];
        o.w = cum[idx.w];
        reinterpret_cast<float4*>(out)[t] = o;
    } else {
        for (int p = base; p < M; ++p) out[p] = cum[ptn[p]];
    }
}

extern "C" void kernel_launch(void* const* d_in, const int* in_sizes, int n_in,
                              void* d_out, int out_size, void* d_ws, size_t ws_size,
                              hipStream_t stream) {
    const float* attrs   = (const float*)d_in[0];   // (N,6)
    const float* weight  = (const float*)d_in[1];   // (6,)
    const float* bias    = (const float*)d_in[2];   // (1,)
    const float* residue = (const float*)d_in[3];   // (N,)
    const int*   parent  = (const int*)d_in[4];     // (N+1,)
    const int*   ptn     = (const int*)d_in[5];     // (H*W,)
    float* out = (float*)d_out;

    const int N  = in_sizes[3];
    const int HW = in_sizes[5];

    const int BLK = 256;
    const size_t packedBytes = (size_t)(N + 1) * 8;

    int2*  packed = (int2*)d_ws;
    float* cum    = (float*)((char*)d_ws + packedBytes);

    // 1) gate + pack
    int g1 = (N + 1 + BLK - 1) / BLK;
    k_gate_pack<<<g1, BLK, 0, stream>>>(attrs, weight, bias, residue, parent,
                                        packed, N);

    // 2) leveled walk: cutoffs 16K / 256K / N
    int c0 = 16384;   if (c0 > N) c0 = N;
    int c1 = 262144;  if (c1 > N) c1 = N;

    int g20 = (c0 + BLK - 1) / BLK;
    k_walk_lvl0<<<g20, BLK, 0, stream>>>(packed, cum, c0, N);
    if (c1 > c0) {
        int n1 = c1 - c0;
        int g21 = (n1 + BLK - 1) / BLK;
        k_walk_lvl<<<g21, BLK, 0, stream>>>(packed, cum, c0, c1, c0);
    }
    if (N > c1) {
        int n2 = N - c1;
        int g22 = (n2 + BLK - 1) / BLK;
        k_walk_lvl<<<g22, BLK, 0, stream>>>(packed, cum, c1, N, c1);
    }

    // 3) pixel gather
    int nQuads = (HW + 3) / 4;
    int g3 = (nQuads + BLK - 1) / BLK;
    k_pixel_gather<<<g3, BLK, 0, stream>>>(cum, ptn, out, HW);
}